// Round 6
// baseline (498.322 us; speedup 1.0000x reference)
//
#include <hip/hip_runtime.h>
#include <math.h>

typedef int    intx8    __attribute__((ext_vector_type(8)));   // 8 dwords = 32 fp8
typedef float  floatx16 __attribute__((ext_vector_type(16)));  // MFMA 32x32 C/D

#define N_ROWS 8192
#define H_DIM  1024
#define V_DIM  32000
#define V_PAD  32768         // padded V: pad cols killed via bias = -1e30
#define IGNORE_INDEX (-100)

#define S_SPLITS 16          // 16 splits x 16 tiles x 128 cols = 32768
#define TILES_PER_SPLIT 16
#define BM 256
#define BN 128
#define BK 64                // one K-step = one mfma_scale K; dbuf per step

#define LOG2E 1.4426950408889634f
#define LN2   0.6931471805599453f

// ---------- fused prep: W-convert | x-convert | bias-pad | target-logit ----------
// fp32 [R][1024] -> fp8 e4m3 "unit-transposed" [64 k-units][Rstride][16B].
__device__ __forceinline__ void conv_one(const float* __restrict__ in,
                                         unsigned char* __restrict__ out,
                                         int r, int u, int Rstride, float scale) {
  const float4* src = (const float4*)(in + (size_t)r * H_DIM + u * 16);
  uint4 res;
#pragma unroll
  for (int j = 0; j < 4; ++j) {
    const float4 v = src[j];
    int p = __builtin_amdgcn_cvt_pk_fp8_f32(v.x * scale, v.y * scale, 0, false);
    p = __builtin_amdgcn_cvt_pk_fp8_f32(v.z * scale, v.w * scale, p, true);
    ((int*)&res)[j] = p;
  }
  *(uint4*)(out + ((size_t)u * Rstride + r) * 16) = res;
}

// One launch, one drain: W convert (8000 blocks, first so it starts immediately),
// x convert (2048), bias pad (128), exact-fp32 target logits (2048).
__global__ __launch_bounds__(256) void prep_all(const float* __restrict__ x,
                                                const float* __restrict__ wgt,
                                                const float* __restrict__ bias,
                                                const int* __restrict__ target,
                                                unsigned char* __restrict__ xs8,
                                                unsigned char* __restrict__ ws8,
                                                float* __restrict__ biasp,
                                                float* __restrict__ tgt_logit) {
  const int bid = blockIdx.x;
  const int tid = threadIdx.x;
  if (bid < 8000) {                         // W: 125 x 64 (u)
    conv_one(wgt, ws8, (bid % 125) * 256 + tid, bid / 125, V_PAD, 1.0f);
  } else if (bid < 10048) {                 // x: 32 x 64, pre-scaled by log2e
    const int b = bid - 8000;
    conv_one(x, xs8, (b % 32) * 256 + tid, b / 32, N_ROWS, LOG2E);
  } else if (bid < 10176) {                 // bias pad (base-2 domain)
    const int i = (bid - 10048) * 256 + tid;
    biasp[i] = (i < V_DIM) ? bias[i] * LOG2E : -1e30f;
  } else {                                  // tgt: one wave per row
    const int r = (bid - 10176) * 4 + (tid >> 6);
    const int lane = tid & 63;
    const int t = target[r];
    const int tt = (t == IGNORE_INDEX) ? 0 : t;
    const float4* xr = (const float4*)(x + (size_t)r * H_DIM);
    const float4* wr = (const float4*)(wgt + (size_t)tt * H_DIM);
    float acc = 0.f;
#pragma unroll
    for (int i = 0; i < 4; ++i) {
      const float4 a = xr[lane + i * 64];
      const float4 b = wr[lane + i * 64];
      acc += a.x * b.x + a.y * b.y + a.z * b.z + a.w * b.w;
    }
#pragma unroll
    for (int off = 32; off >= 1; off >>= 1) acc += __shfl_xor(acc, off, 64);
    if (lane == 0) tgt_logit[r] = acc + bias[tt];
  }
}

// ---------- main fused GEMM + sumexp ----------
// fp8 e4m3, x pre-scaled by log2e. mfma_scale_f32_32x32x64_f8f6f4, unity scales.
// Double-buffered LDS (2 x 24KB), ONE barrier per K-step: DMA(f+1) issued BEFORE
// the MFMA block, so the compiler's vmcnt(0)-before-s_barrier drains loads that
// have had the whole MFMA phase (~1100cyc) in flight -> drain ~free. This is the
// restructure the 2-barrier shape (r5: 43% MfmaUtil) couldn't express.
__global__ __launch_bounds__(256, 2) void flce_main(const unsigned char* __restrict__ xs,
                                                    const unsigned char* __restrict__ wsb,
                                                    const float* __restrict__ biasp,
                                                    float* __restrict__ partials) {
  __shared__ __align__(16) unsigned char smA[2][4 * 256 * 16];  // 2 x 16KB [u][row][16B]
  __shared__ __align__(16) unsigned char smB[2][4 * 128 * 16];  // 2 x 8KB

  const int tid  = threadIdx.x;
  const int lane = tid & 63;
  const int w    = tid >> 6;      // wave 0..3: rows [w*64, w*64+64)
  const int l31  = lane & 31;
  const int half = lane >> 5;     // k-half within MFMA (32 k each)
  const int wr   = w * 64;
  const int row0 = blockIdx.x * BM;
  const int sidx = blockIdx.y;

  float l_state[32];              // slot = mb*16 + reg; per-lane Σ 2^v over its cols
#pragma unroll
  for (int i = 0; i < 32; ++i) l_state[i] = 0.f;

  floatx16 acc[2][4];
#pragma unroll
  for (int mb = 0; mb < 2; ++mb)
#pragma unroll
    for (int nb = 0; nb < 4; ++nb)
#pragma unroll
      for (int i = 0; i < 16; ++i) acc[mb][nb][i] = 0.f;

  // DMA one BK=64 step (4 k-units): A 16 chunks + B 8 chunks, 1KB wave-DMAs.
  auto issue_dma = [&](int f, int p) {
    const int ct = f >> 4;
    const int k  = f & 15;
    const int n0 = (sidx * TILES_PER_SPLIT + ct) * BN;
    const int ub = k * 4;
#pragma unroll
    for (int j = 0; j < 4; ++j) {            // A: c = j*4+w -> u = c>>2, rb = c&3
      const int c = j * 4 + w;
      const int u = c >> 2;
      const int rb = c & 3;
      __builtin_amdgcn_global_load_lds(
          (const __attribute__((address_space(1))) void*)(xs + ((size_t)(ub + u) * N_ROWS + row0 + rb * 64 + lane) * 16),
          (__attribute__((address_space(3))) void*)(smA[p] + ((u * 256 + rb * 64 + lane) * 16)),
          16, 0, 0);
    }
#pragma unroll
    for (int j = 0; j < 2; ++j) {            // B: c = j*4+w -> u = c>>1, rb = c&1
      const int c = j * 4 + w;
      const int u = c >> 1;
      const int rb = c & 1;
      __builtin_amdgcn_global_load_lds(
          (const __attribute__((address_space(1))) void*)(wsb + ((size_t)(ub + u) * V_PAD + n0 + rb * 64 + lane) * 16),
          (__attribute__((address_space(3))) void*)(smB[p] + ((u * 128 + rb * 64 + lane) * 16)),
          16, 0, 0);
    }
  };

  issue_dma(0, 0);
  __syncthreads();                           // land step 0

  float bnb[4];
  const int ua = half * 2;                   // this lane-half's 2 k-units

#pragma unroll 1
  for (int f = 0; f < TILES_PER_SPLIT * 16; ++f) {   // 256 flat steps (tile = 16 steps)
    const int p = f & 1;
    if (f + 1 < TILES_PER_SPLIT * 16) issue_dma(f + 1, p ^ 1);

    if ((f & 15) == 0) {                     // prefetch this tile's bias (hidden by MFMA)
      const int n0 = (sidx * TILES_PER_SPLIT + (f >> 4)) * BN;
#pragma unroll
      for (int nb = 0; nb < 4; ++nb) bnb[nb] = biasp[n0 + nb * 32 + l31];
    }

    union { intx8 v; uint4 q[2]; } a[2], b[4];
#pragma unroll
    for (int mb = 0; mb < 2; ++mb) {
      a[mb].q[0] = *(const uint4*)(smA[p] + ((ua * 256 + wr + mb * 32 + l31) * 16));
      a[mb].q[1] = *(const uint4*)(smA[p] + (((ua + 1) * 256 + wr + mb * 32 + l31) * 16));
    }
#pragma unroll
    for (int nb = 0; nb < 4; ++nb) {
      b[nb].q[0] = *(const uint4*)(smB[p] + ((ua * 128 + nb * 32 + l31) * 16));
      b[nb].q[1] = *(const uint4*)(smB[p] + (((ua + 1) * 128 + nb * 32 + l31) * 16));
    }
#pragma unroll
    for (int mb = 0; mb < 2; ++mb)
#pragma unroll
      for (int nb = 0; nb < 4; ++nb)
        acc[mb][nb] = __builtin_amdgcn_mfma_scale_f32_32x32x64_f8f6f4(
            a[mb].v, b[nb].v, acc[mb][nb],
            0, 0,                      // fp8 e4m3 A and B
            0, 0x7F7F7F7F,             // scale A = 1.0 (E8M0 127 = 2^0)
            0, 0x7F7F7F7F);            // scale B = 1.0

    if ((f & 15) == 15) {
      // Tile epilogue: Σ 2^(acc + bias2), raw v_exp_f32 (values bounded, no clamp needed).
      // C/D 32x32 layout: col = nb*32 + l31, row = wr + mb*32 + 4*half + (r&3) + 8*(r>>2).
#pragma unroll
      for (int mb = 0; mb < 2; ++mb)
#pragma unroll
        for (int r = 0; r < 16; ++r) {
          l_state[mb * 16 + r] += __builtin_amdgcn_exp2f(acc[mb][0][r] + bnb[0])
                                + __builtin_amdgcn_exp2f(acc[mb][1][r] + bnb[1])
                                + __builtin_amdgcn_exp2f(acc[mb][2][r] + bnb[2])
                                + __builtin_amdgcn_exp2f(acc[mb][3][r] + bnb[3]);
        }
#pragma unroll
      for (int mb = 0; mb < 2; ++mb)
#pragma unroll
        for (int nb = 0; nb < 4; ++nb)
#pragma unroll
          for (int i = 0; i < 16; ++i) acc[mb][nb][i] = 0.f;
    }
    __syncthreads();   // drains DMA(f+1) after the MFMA phase; also guards buffer reuse
  }

  // Sum over this wave's 128 cols: butterfly within the 32-lane half.
#pragma unroll
  for (int s = 0; s < 32; ++s) {
    float v = l_state[s];
#pragma unroll
    for (int off = 1; off < 32; off <<= 1) v += __shfl_xor(v, off, 64);
    l_state[s] = v;
  }

  // Each wave owns all cols of its 64 rows -> direct write.
  if (l31 == 0) {
#pragma unroll
    for (int s = 0; s < 32; ++s) {
      const int mb = s >> 4, r = s & 15;
      const int row = wr + mb * 32 + 4 * half + (r & 3) + 8 * (r >> 2);
      partials[(size_t)(row0 + row) * S_SPLITS + sidx] = l_state[s];
    }
  }
}

// Per-row loss + per-block partial sums. partials hold Σ2^v per (row, split):
// lse_nat = ln2 * log2(Σ_s l_s).
__global__ __launch_bounds__(256) void loss_rows(const float* __restrict__ partials,
                                                 const float* __restrict__ tgt_logit,
                                                 const int* __restrict__ target,
                                                 float* __restrict__ bsums) {
  const int r = blockIdx.x * 256 + threadIdx.x;
  float l = 0.f;
#pragma unroll
  for (int s = 0; s < S_SPLITS; ++s) l += partials[(size_t)r * S_SPLITS + s];
  const float lse = LN2 * __log2f(l);
  const bool valid = (target[r] != IGNORE_INDEX);
  float loss = valid ? (lse - tgt_logit[r]) : 0.f;
  float cnt  = valid ? 1.f : 0.f;
  const int lane = threadIdx.x & 63;
  const int w = threadIdx.x >> 6;
#pragma unroll
  for (int off = 32; off >= 1; off >>= 1) {
    loss += __shfl_xor(loss, off, 64);
    cnt  += __shfl_xor(cnt, off, 64);
  }
  __shared__ float sl[4], sc[4];
  if (lane == 0) { sl[w] = loss; sc[w] = cnt; }
  __syncthreads();
  if (threadIdx.x == 0) {
    float S = 0.f, C = 0.f;
    for (int i = 0; i < 4; ++i) { S += sl[i]; C += sc[i]; }
    bsums[blockIdx.x] = S;
    bsums[32 + blockIdx.x] = C;
  }
}

__global__ void finalize(const float* __restrict__ bsums, float* __restrict__ out) {
  const int t = threadIdx.x;  // 64 threads
  float s = (t < 32) ? bsums[t] : 0.f;
  float c = (t < 32) ? bsums[32 + t] : 0.f;
#pragma unroll
  for (int off = 32; off >= 1; off >>= 1) {
    s += __shfl_xor(s, off, 64);
    c += __shfl_xor(c, off, 64);
  }
  if (t == 0) out[0] = s / fmaxf(c, 1.f);
}

extern "C" void kernel_launch(void* const* d_in, const int* in_sizes, int n_in,
                              void* d_out, int out_size, void* d_ws, size_t ws_size,
                              hipStream_t stream) {
  const float* x    = (const float*)d_in[0];
  const float* wgt  = (const float*)d_in[1];
  const float* bias = (const float*)d_in[2];
  const int*   tgt  = (const int*)d_in[3];
  float* out = (float*)d_out;

  char* ws = (char*)d_ws;
  const size_t XS8 = (size_t)N_ROWS * H_DIM;        // 8 MB fp8 x (pre-scaled by log2e)
  const size_t WS8 = (size_t)V_PAD * H_DIM;         // 33.5 MB fp8 W (pad rows stay poisoned)
  const size_t BP  = (size_t)V_PAD * 4;             // padded bias (base-2 domain)
  const size_t PB  = (size_t)N_ROWS * S_SPLITS * 4; // per-(row,split) sumexp
  unsigned char* xs8 = (unsigned char*)ws;
  unsigned char* ws8 = (unsigned char*)(ws + XS8);
  float* biasp    = (float*)(ws + XS8 + WS8);
  float* partials = (float*)(ws + XS8 + WS8 + BP);
  float* tgt_lg   = (float*)(ws + XS8 + WS8 + BP + PB);
  float* bsums    = (float*)(ws + XS8 + WS8 + BP + PB + (size_t)N_ROWS * 4);

  prep_all<<<12224, 256, 0, stream>>>(x, wgt, bias, tgt, xs8, ws8, biasp, tgt_lg);
  flce_main<<<dim3(N_ROWS / BM, S_SPLITS), 256, 0, stream>>>(xs8, ws8, biasp, partials);
  loss_rows<<<N_ROWS / 256, 256, 0, stream>>>(partials, tgt_lg, tgt, bsums);
  finalize<<<1, 64, 0, stream>>>(bsums, out);
}